// Round 14
// baseline (401.459 us; speedup 1.0000x reference)
//
#include <hip/hip_runtime.h>
#include <cmath>

#define Bc 2
#define Sc 2048
#define Dc 1024
#define Hc 16
#define DKc 64
#define DFFc 4096
#define NT (Sc / 128)

typedef __bf16    bfx8 __attribute__((ext_vector_type(8)));
typedef __bf16    bfx4 __attribute__((ext_vector_type(4)));
typedef float     fx4  __attribute__((ext_vector_type(4)));

#define QSC 0.18033688011112042f   // 0.125 * log2(e)

__device__ inline void gload_lds16(const void* g, void* l) {
  __builtin_amdgcn_global_load_lds((const __attribute__((address_space(1))) void*)g,
                                   (__attribute__((address_space(3))) void*)l, 16, 0, 0);
}

enum { M_QKV = 0, M_GELU = 3 };

// st_16x32-style fragment read (1 KB per 16-row x 32-col subtile)
__device__ inline bfx8 rd_frag(const char* matbase, int r, int kk) {
  int inner = (r & 15) * 64 + (kk & 31) * 2;
  int byte = (((r >> 4) * 2 + (kk >> 5)) << 10) + (inner ^ ((r & 8) ? 32 : 0));
  return *(const bfx8*)(matbase + byte);
}

// ---------------- 256x256 8-phase GEMM (T2+T3+T4+T5) ----------------
template<int MODE>
__global__ __launch_bounds__(512, 2)
void gemm8(const __bf16* __restrict__ A, const __bf16* __restrict__ Bw,
           const float* __restrict__ bias, const float* __restrict__ bias2,
           const float* __restrict__ bias3,
           void* __restrict__ outp, void* __restrict__ outp2,
           void* __restrict__ outp3, int M, int N, int K)
{
  __shared__ char lds[131072];
  const int tid = threadIdx.x, wave = tid >> 6, lane = tid & 63;
  const int l16 = lane & 15, l4 = lane >> 4;
  const int wr = wave >> 2, wc = wave & 3;

  const int gx = gridDim.x, nwg = gx * gridDim.y;
  const int bid = blockIdx.y * gx + blockIdx.x;
  const int swz = (bid & 7) * (nwg >> 3) + (bid >> 3);
  const int bm = (swz / gx) * 256, bn = (swz % gx) * 256;

  const int nkt = K >> 6;

  fx4 acc[8][4] = {};

  auto stage_tile = [&](int kt, int buf) {
#pragma unroll
    for (int u = 0; u < 4; ++u) {
      const __bf16* gsrc = (u < 2 ? A + (long)(bm + (u & 1) * 128) * K
                                  : Bw + (long)(bn + (u & 1) * 128) * K) + kt * 64;
      char* dst = lds + (u < 2 ? 0 : 65536) + buf * 32768 + (u & 1) * 16384;
#pragma unroll
      for (int i = 0; i < 2; ++i) {
        int c = i * 512 + tid;
        int sc = c ^ (((c >> 5) & 1) << 1);
        int s = sc >> 6, rin = (sc & 63) >> 2, cch = sc & 3;
        gload_lds16(gsrc + (long)((s >> 1) * 16 + rin) * K + (s & 1) * 32 + cch * 8,
                    dst + c * 16);
      }
    }
  };

  stage_tile(0, 0);
  asm volatile("s_waitcnt vmcnt(0)" ::: "memory");
  __builtin_amdgcn_s_barrier();

  bfx8 af[4][2], bfA[2][2], bfB[2][2];

  for (int kt = 0; kt < nkt; ++kt) {
    const int buf = kt & 1;
    const char* Ab = lds + buf * 32768;
    const char* Bb = lds + 65536 + buf * 32768;

#pragma unroll
    for (int m = 0; m < 4; ++m)
#pragma unroll
      for (int ks = 0; ks < 2; ++ks)
        af[m][ks] = rd_frag(Ab, wr * 128 + m * 16 + l16, ks * 32 + l4 * 8);
#pragma unroll
    for (int n = 0; n < 2; ++n)
#pragma unroll
      for (int ks = 0; ks < 2; ++ks)
        bfA[n][ks] = rd_frag(Bb, wc * 64 + n * 16 + l16, ks * 32 + l4 * 8);
    if (kt + 1 < nkt) stage_tile(kt + 1, buf ^ 1);
    __builtin_amdgcn_s_barrier();
    __builtin_amdgcn_s_setprio(1);
#pragma unroll
    for (int m = 0; m < 4; ++m)
#pragma unroll
      for (int n = 0; n < 2; ++n)
#pragma unroll
        for (int ks = 0; ks < 2; ++ks)
          acc[m][n] = __builtin_amdgcn_mfma_f32_16x16x32_bf16(af[m][ks], bfA[n][ks], acc[m][n], 0, 0, 0);
    __builtin_amdgcn_s_setprio(0);
    __builtin_amdgcn_s_barrier();

#pragma unroll
    for (int n = 0; n < 2; ++n)
#pragma unroll
      for (int ks = 0; ks < 2; ++ks)
        bfB[n][ks] = rd_frag(Bb, wc * 64 + 32 + n * 16 + l16, ks * 32 + l4 * 8);
    __builtin_amdgcn_s_barrier();
    __builtin_amdgcn_s_setprio(1);
#pragma unroll
    for (int m = 0; m < 4; ++m)
#pragma unroll
      for (int n = 0; n < 2; ++n)
#pragma unroll
        for (int ks = 0; ks < 2; ++ks)
          acc[m][2 + n] = __builtin_amdgcn_mfma_f32_16x16x32_bf16(af[m][ks], bfB[n][ks], acc[m][2 + n], 0, 0, 0);
    __builtin_amdgcn_s_setprio(0);
    __builtin_amdgcn_s_barrier();

#pragma unroll
    for (int m = 0; m < 4; ++m)
#pragma unroll
      for (int ks = 0; ks < 2; ++ks)
        af[m][ks] = rd_frag(Ab, wr * 128 + 64 + m * 16 + l16, ks * 32 + l4 * 8);
    __builtin_amdgcn_s_barrier();
    __builtin_amdgcn_s_setprio(1);
#pragma unroll
    for (int m = 0; m < 4; ++m)
#pragma unroll
      for (int n = 0; n < 2; ++n)
#pragma unroll
        for (int ks = 0; ks < 2; ++ks)
          acc[4 + m][n] = __builtin_amdgcn_mfma_f32_16x16x32_bf16(af[m][ks], bfA[n][ks], acc[4 + m][n], 0, 0, 0);
    __builtin_amdgcn_s_setprio(0);
    __builtin_amdgcn_s_barrier();

    __builtin_amdgcn_s_setprio(1);
#pragma unroll
    for (int m = 0; m < 4; ++m)
#pragma unroll
      for (int n = 0; n < 2; ++n)
#pragma unroll
        for (int ks = 0; ks < 2; ++ks)
          acc[4 + m][2 + n] = __builtin_amdgcn_mfma_f32_16x16x32_bf16(af[m][ks], bfB[n][ks], acc[4 + m][2 + n], 0, 0, 0);
    __builtin_amdgcn_s_setprio(0);
    asm volatile("s_waitcnt vmcnt(0)" ::: "memory");
    __builtin_amdgcn_sched_barrier(0);
    __builtin_amdgcn_s_barrier();
  }

#pragma unroll
  for (int m = 0; m < 8; ++m) {
#pragma unroll
    for (int n = 0; n < 4; ++n) {
      const int gr0 = bm + wr * 128 + m * 16 + l4 * 4;
      const int gc  = bn + wc * 64 + n * 16 + l16;
      float bv;
      if constexpr (MODE == M_QKV)
        bv = (gc < 1024) ? bias[gc] : (gc < 2048) ? bias2[gc - 1024] : bias3[gc - 2048];
      else
        bv = bias[gc];
#pragma unroll
      for (int j = 0; j < 4; ++j) {
        const int gr = gr0 + j;
        float v = acc[m][n][j] + bv;
        if constexpr (MODE == M_QKV) {
          int qkv = gc >> 10, col = gc & 1023;
          int b = gr >> 11, s = gr & 2047, h = col >> 6, dk = col & 63;
          if (qkv == 0)   // Q pre-scaled by 0.125*log2(e) so fattn uses exp2
            ((__bf16*)outp)[(((long)(b * Hc + h)) * Sc + s) * DKc + dk] = (__bf16)(v * QSC);
          else if (qkv == 1)
            ((__bf16*)outp2)[(((long)(b * Hc + h)) * Sc + s) * DKc + dk] = (__bf16)v;
          else
            ((__bf16*)outp3)[(((long)(b * Hc + h)) * DKc + dk) * Sc + s] = (__bf16)v;
        } else { // M_GELU
          float t = 0.5f * v * (1.0f + erff(v * 0.70710678118654752f));
          ((__bf16*)outp)[(long)gr * N + gc] = (__bf16)t;
        }
      }
    }
  }
}

// ---- 256x128 8-phase split-K GEMM -> f32 partials (nt store) ----
__global__ __launch_bounds__(512, 2)
void gemm8_sk(const __bf16* __restrict__ A, const __bf16* __restrict__ Bw,
              float* __restrict__ rawp, int M, int N, int K, int kchunk)
{
  __shared__ char lds[98304];
  const int tid = threadIdx.x, wave = tid >> 6, lane = tid & 63;
  const int l16 = lane & 15, l4 = lane >> 4;
  const int wr = wave >> 2, wc = wave & 3;

  const int gx = gridDim.x, nwg = gx * gridDim.y;
  const int bid = blockIdx.y * gx + blockIdx.x;
  const int swz = (bid & 7) * (nwg >> 3) + (bid >> 3);
  const int bm = (swz / gx) * 256, bn = (swz % gx) * 128;
  const int kz = blockIdx.z;
  const int kt0 = (kz * kchunk) >> 6;
  const int nkt = kchunk >> 6;

  fx4 acc[8][2] = {};

  auto stage_tile = [&](int kt, int buf) {
#pragma unroll
    for (int u = 0; u < 3; ++u) {
      const __bf16* gsrc = (u < 2 ? A + (long)(bm + u * 128) * K
                                  : Bw + (long)bn * K) + kt * 64;
      char* dst = (u < 2) ? lds + buf * 32768 + u * 16384
                          : lds + 65536 + buf * 16384;
#pragma unroll
      for (int i = 0; i < 2; ++i) {
        int c = i * 512 + tid;
        int sc = c ^ (((c >> 5) & 1) << 1);
        int s = sc >> 6, rin = (sc & 63) >> 2, cch = sc & 3;
        gload_lds16(gsrc + (long)((s >> 1) * 16 + rin) * K + (s & 1) * 32 + cch * 8,
                    dst + c * 16);
      }
    }
  };

  stage_tile(kt0, 0);
  asm volatile("s_waitcnt vmcnt(0)" ::: "memory");
  __builtin_amdgcn_s_barrier();

  bfx8 af[4][2], bfA[2], bfB[2];

  for (int t = 0; t < nkt; ++t) {
    const int buf = t & 1;
    const char* Ab = lds + buf * 32768;
    const char* Bb = lds + 65536 + buf * 16384;

#pragma unroll
    for (int m = 0; m < 4; ++m)
#pragma unroll
      for (int ks = 0; ks < 2; ++ks)
        af[m][ks] = rd_frag(Ab, wr * 128 + m * 16 + l16, ks * 32 + l4 * 8);
#pragma unroll
    for (int ks = 0; ks < 2; ++ks)
      bfA[ks] = rd_frag(Bb, wc * 32 + l16, ks * 32 + l4 * 8);
    if (t + 1 < nkt) stage_tile(kt0 + t + 1, buf ^ 1);
    __builtin_amdgcn_s_barrier();
    __builtin_amdgcn_s_setprio(1);
#pragma unroll
    for (int m = 0; m < 4; ++m)
#pragma unroll
      for (int ks = 0; ks < 2; ++ks)
        acc[m][0] = __builtin_amdgcn_mfma_f32_16x16x32_bf16(af[m][ks], bfA[ks], acc[m][0], 0, 0, 0);
    __builtin_amdgcn_s_setprio(0);
    __builtin_amdgcn_s_barrier();

#pragma unroll
    for (int ks = 0; ks < 2; ++ks)
      bfB[ks] = rd_frag(Bb, wc * 32 + 16 + l16, ks * 32 + l4 * 8);
    __builtin_amdgcn_s_barrier();
    __builtin_amdgcn_s_setprio(1);
#pragma unroll
    for (int m = 0; m < 4; ++m)
#pragma unroll
      for (int ks = 0; ks < 2; ++ks)
        acc[m][1] = __builtin_amdgcn_mfma_f32_16x16x32_bf16(af[m][ks], bfB[ks], acc[m][1], 0, 0, 0);
    __builtin_amdgcn_s_setprio(0);
    __builtin_amdgcn_s_barrier();

#pragma unroll
    for (int m = 0; m < 4; ++m)
#pragma unroll
      for (int ks = 0; ks < 2; ++ks)
        af[m][ks] = rd_frag(Ab, wr * 128 + 64 + m * 16 + l16, ks * 32 + l4 * 8);
    __builtin_amdgcn_s_barrier();
    __builtin_amdgcn_s_setprio(1);
#pragma unroll
    for (int m = 0; m < 4; ++m)
#pragma unroll
      for (int ks = 0; ks < 2; ++ks)
        acc[4 + m][0] = __builtin_amdgcn_mfma_f32_16x16x32_bf16(af[m][ks], bfA[ks], acc[4 + m][0], 0, 0, 0);
    __builtin_amdgcn_s_setprio(0);
    __builtin_amdgcn_s_barrier();

    __builtin_amdgcn_s_setprio(1);
#pragma unroll
    for (int m = 0; m < 4; ++m)
#pragma unroll
      for (int ks = 0; ks < 2; ++ks)
        acc[4 + m][1] = __builtin_amdgcn_mfma_f32_16x16x32_bf16(af[m][ks], bfB[ks], acc[4 + m][1], 0, 0, 0);
    __builtin_amdgcn_s_setprio(0);
    asm volatile("s_waitcnt vmcnt(0)" ::: "memory");
    __builtin_amdgcn_sched_barrier(0);
    __builtin_amdgcn_s_barrier();
  }

#pragma unroll
  for (int m = 0; m < 8; ++m) {
#pragma unroll
    for (int n = 0; n < 2; ++n) {
      const int gr0 = bm + wr * 128 + m * 16 + l4 * 4;
      const int gc  = bn + wc * 32 + n * 16 + l16;
#pragma unroll
      for (int j = 0; j < 4; ++j)
        __builtin_nontemporal_store(acc[m][n][j],
            &rawp[(long)kz * M * N + (long)(gr0 + j) * N + gc]);
    }
  }
}

// -------- fused two-pass flash attention, QBLK=128, 8 waves ----------
// grid (16, 32) = 512 blocks; z-local XCD remap: 4 z's x 16 q-blocks per XCD.
__global__ __launch_bounds__(512)
void fattn(const __bf16* __restrict__ Qg, const __bf16* __restrict__ Kg,
           const __bf16* __restrict__ Vg, const unsigned long long* __restrict__ pk,
           float* __restrict__ wout, __bf16* __restrict__ aout)
{
  const int bid = blockIdx.y * 16 + blockIdx.x;
  const int c = bid & 7, idx = bid >> 3;
  const int z = c + 8 * (idx >> 4);        // 4 z's per XCD: K+V = 4 MB = L2
  const int qb = (idx & 15) * 128;
  const int bz = z >> 4, h = z & 15;
  const int tid = threadIdx.x, w = tid >> 6, lane = tid & 63;
  const int l16 = lane & 15, l4 = lane >> 4;

  __shared__ alignas(16) __bf16 Qs[128 * 64];      // 16 KB  src-swizzled
  __shared__ alignas(16) __bf16 Ks[2][128 * 64];   // 32 KB  double-buffered
  __shared__ alignas(16) __bf16 Vs[64 * 128];      // 16 KB  [dk][k]
  __shared__ alignas(16) __bf16 Ps[128 * 136];     // 34 KB  [q][k] +8 pad

  const __bf16* Qz = Qg + ((long)z * Sc + qb) * DKc;
  const __bf16* Kz = Kg + (long)z * Sc * DKc;
  const __bf16* Vz = Vg + (long)z * DKc * Sc;

  auto stageK = [&](int kt, int buf) {
#pragma unroll
    for (int i = 0; i < 2; ++i) {
      int ch = i * 512 + tid;
      int row = ch >> 3, c16 = ch & 7;
      gload_lds16(Kz + (long)(kt * 128 + row) * DKc + ((c16 ^ (row & 7)) * 8),
                  (char*)Ks[buf] + ch * 16);
    }
  };
  auto stageV = [&](int kt) {
#pragma unroll
    for (int i = 0; i < 2; ++i) {
      int ch = i * 512 + tid;
      int row = ch >> 4, c16 = ch & 15;
      gload_lds16(Vz + (long)row * Sc + kt * 128 + ((c16 ^ (row & 7)) * 8),
                  (char*)Vs + ch * 16);
    }
  };

  // prologue: Q (128 rows) + K tile 0
#pragma unroll
  for (int i = 0; i < 2; ++i) {
    int ch = i * 512 + tid;
    int row = ch >> 3, c16 = ch & 7;
    gload_lds16(Qz + (long)row * DKc + ((c16 ^ (row & 7)) * 8), (char*)Qs + ch * 16);
  }
  stageK(0, 0);
  __syncthreads();

  const int qr = w * 16 + l16;
  bfx8 aq[2];
#pragma unroll
  for (int ks = 0; ks < 2; ++ks) {
    int c16 = ks * 4 + l4;
    aq[ks] = *(const bfx8*)((const char*)Qs + qr * 128 + ((c16 ^ (qr & 7)) * 16));
  }

  const long pkbase = ((long)bz * Sc + qb + w * 16 + l4 * 4) * 32;

  float l[4] = {0.f, 0.f, 0.f, 0.f};

  // ---------------- pass A: row denominators (m = 0 proxy) ----------------
  for (int kt = 0; kt < NT; ++kt) {
    const int cur = kt & 1;
    stageK(kt + 1 < NT ? kt + 1 : 0, cur ^ 1);
    fx4 acc[8];
    __builtin_amdgcn_s_setprio(1);
#pragma unroll
    for (int n = 0; n < 8; ++n) {
      int kr = n * 16 + l16;
      fx4 a = {};
#pragma unroll
      for (int ks = 0; ks < 2; ++ks) {
        int c16 = ks * 4 + l4;
        bfx8 bk = *(const bfx8*)((const char*)Ks[cur] + kr * 128 + ((c16 ^ (kr & 7)) * 16));
        a = __builtin_amdgcn_mfma_f32_16x16x32_bf16(aq[ks], bk, a, 0, 0, 0);
      }
      acc[n] = a;
    }
    __builtin_amdgcn_s_setprio(0);
#pragma unroll
    for (int j = 0; j < 4; ++j) {
      unsigned long long m0 = pk[pkbase + j * 32 + kt * 2];
      unsigned long long m1 = pk[pkbase + j * 32 + kt * 2 + 1];
      float ps = 0.f;
#pragma unroll
      for (int n = 0; n < 8; ++n) {
        unsigned long long mw = (n < 4) ? m0 : m1;
        int bit = (n & 3) * 16 + l16;
        float e = exp2f(acc[n][j]);      // Q pre-scaled by 0.125*log2e
        ps += ((mw >> bit) & 1) ? e : 0.f;
      }
      l[j] += ps;
    }
    __syncthreads();
  }

  float invl[4];
#pragma unroll
  for (int j = 0; j < 4; ++j) {
    float s = l[j];
#pragma unroll
    for (int o = 1; o < 16; o <<= 1) s += __shfl_xor(s, o, 64);
    invl[j] = 1.0f / s;
  }

  fx4 O[4] = {};

  // ------------- pass B: weights (nt store) + PV -------------
  for (int kt = 0; kt < NT; ++kt) {
    const int cur = kt & 1;
    stageV(kt);
    fx4 acc[8];
    __builtin_amdgcn_s_setprio(1);
#pragma unroll
    for (int n = 0; n < 8; ++n) {
      int kr = n * 16 + l16;
      fx4 a = {};
#pragma unroll
      for (int ks = 0; ks < 2; ++ks) {
        int c16 = ks * 4 + l4;
        bfx8 bk = *(const bfx8*)((const char*)Ks[cur] + kr * 128 + ((c16 ^ (kr & 7)) * 16));
        a = __builtin_amdgcn_mfma_f32_16x16x32_bf16(aq[ks], bk, a, 0, 0, 0);
      }
      acc[n] = a;
    }
    __builtin_amdgcn_s_setprio(0);
#pragma unroll
    for (int j = 0; j < 4; ++j) {
      unsigned long long m0 = pk[pkbase + j * 32 + kt * 2];
      unsigned long long m1 = pk[pkbase + j * 32 + kt * 2 + 1];
      __bf16* prow = Ps + (w * 16 + l4 * 4 + j) * 136;
#pragma unroll
      for (int n = 0; n < 8; ++n) {
        unsigned long long mw = (n < 4) ? m0 : m1;
        int bit = (n & 3) * 16 + l16;
        float wv = ((mw >> bit) & 1) ? exp2f(acc[n][j]) * invl[j] : 0.f;
        prow[n * 16 + l16] = (__bf16)wv;
      }
    }
    __syncthreads();                      // Ps ready; V(kt) landed
    if (kt + 1 < NT) stageK(kt + 1, cur ^ 1);
    // nontemporal weight store: never re-read -> don't evict K/V from L2
    float* wbase = wout + ((long)z * Sc + qb) * Sc + kt * 128;
#pragma unroll
    for (int it = 0; it < 8; ++it) {
      int idx2 = it * 512 + tid;
      int row = idx2 >> 5, cc = idx2 & 31;
      bfx4 p4 = *(const bfx4*)(Ps + row * 136 + cc * 4);
      fx4 o;
      o[0] = (float)p4[0]; o[1] = (float)p4[1]; o[2] = (float)p4[2]; o[3] = (float)p4[3];
      __builtin_nontemporal_store(o, (fx4*)(wbase + (long)row * Sc + cc * 4));
    }
    __builtin_amdgcn_s_setprio(1);
#pragma unroll
    for (int ks2 = 0; ks2 < 4; ++ks2) {
      bfx8 pa = *(const bfx8*)(Ps + qr * 136 + ks2 * 32 + l4 * 8);
#pragma unroll
      for (int n = 0; n < 4; ++n) {
        int vr = n * 16 + l16;
        int c16 = ks2 * 4 + l4;
        bfx8 bv = *(const bfx8*)((const char*)Vs + vr * 256 + ((c16 ^ (vr & 7)) * 16));
        O[n] = __builtin_amdgcn_mfma_f32_16x16x32_bf16(pa, bv, O[n], 0, 0, 0);
      }
    }
    __builtin_amdgcn_s_setprio(0);
    __syncthreads();
  }

#pragma unroll
  for (int n = 0; n < 4; ++n) {
#pragma unroll
    for (int j = 0; j < 4; ++j) {
      int qg = qb + w * 16 + l4 * 4 + j;
      aout[((long)bz * Sc + qg) * Dc + h * DKc + n * 16 + l16] = (__bf16)O[n][j];
    }
  }
}

__device__ inline float waveSum(float v) {
#pragma unroll
  for (int o = 32; o > 0; o >>= 1) v += __shfl_xor(v, o, 64);
  return v;
}

// LayerNorm combining split-K partials + bias + bf16 residual
__global__ __launch_bounds__(256)
void ln_comb(const float* __restrict__ p0, const float* __restrict__ p1,
             const float* __restrict__ bias, const __bf16* __restrict__ resid,
             const float* __restrict__ g, const float* __restrict__ be,
             __bf16* __restrict__ ob, float* __restrict__ of)
{
  const long row = blockIdx.x;
  const int tid = threadIdx.x, wave = tid >> 6, lane = tid & 63;
  fx4 a = *(const fx4*)(p0 + row * Dc + tid * 4);
  fx4 b = *(const fx4*)(p1 + row * Dc + tid * 4);
  fx4 bi = *(const fx4*)(bias + tid * 4);
  bfx4 r4 = *(const bfx4*)(resid + row * Dc + tid * 4);
  const float v0 = a[0] + b[0] + bi[0] + (float)r4[0];
  const float v1 = a[1] + b[1] + bi[1] + (float)r4[1];
  const float v2 = a[2] + b[2] + bi[2] + (float)r4[2];
  const float v3 = a[3] + b[3] + bi[3] + (float)r4[3];
  float s = v0 + v1 + v2 + v3;
  s = waveSum(s);
  __shared__ float sm[4];
  if (lane == 0) sm[wave] = s;
  __syncthreads();
  const float mean = (sm[0] + sm[1] + sm[2] + sm[3]) * (1.0f / Dc);
  const float d0 = v0 - mean, d1 = v1 - mean, d2 = v2 - mean, d3 = v3 - mean;
  float q = d0 * d0 + d1 * d1 + d2 * d2 + d3 * d3;
  q = waveSum(q);
  __syncthreads();
  if (lane == 0) sm[wave] = q;
  __syncthreads();
  const float var = (sm[0] + sm[1] + sm[2] + sm[3]) * (1.0f / (Dc - 1));
  const float inv = 1.0f / (sqrtf(var) + 1e-6f);
  const float r0 = g[tid * 4 + 0] * d0 * inv + be[tid * 4 + 0];
  const float r1 = g[tid * 4 + 1] * d1 * inv + be[tid * 4 + 1];
  const float r2 = g[tid * 4 + 2] * d2 * inv + be[tid * 4 + 2];
  const float r3 = g[tid * 4 + 3] * d3 * inv + be[tid * 4 + 3];
  if (ob) {
    bfx4 o; o[0] = (__bf16)r0; o[1] = (__bf16)r1; o[2] = (__bf16)r2; o[3] = (__bf16)r3;
    *(bfx4*)(ob + row * Dc + tid * 4) = o;
  }
  if (of) {
    fx4 o; o[0] = r0; o[1] = r1; o[2] = r2; o[3] = r3;
    *(fx4*)(of + row * Dc + tid * 4) = o;
  }
}

// casts (blocks 0..16383) + mask bit-pack (blocks 16384..49151)
__global__ __launch_bounds__(256)
void prep(const float* __restrict__ w1, const float* __restrict__ w2,
          const float* __restrict__ x,  const float* __restrict__ wq,
          const float* __restrict__ wk, const float* __restrict__ wv,
          const float* __restrict__ wo, const int* __restrict__ mask,
          __bf16* __restrict__ W1B, __bf16* __restrict__ W2B,
          __bf16* __restrict__ XB,  __bf16* __restrict__ WQKV,
          __bf16* __restrict__ WOB, unsigned long long* __restrict__ pkk)
{
  const int bidx = blockIdx.x;
  if (bidx >= 16384) {
    long wid = (long)(bidx - 16384) * 4 + (threadIdx.x >> 6);
    int lane = threadIdx.x & 63;
    int v = mask[wid * 64 + lane];
    unsigned long long b = __ballot(v != 0);
    if (lane == 0) pkk[wid] = b;
    return;
  }
  const long M4 = 4ll * 1024 * 1024, M1 = 1024 * 1024;
  long i = ((long)bidx * 256 + threadIdx.x) * 4;
  const float* src; __bf16* dst; long off;
  if      (i < M4)          { src = w1; dst = W1B;           off = i; }
  else if (i < 2 * M4)      { src = w2; dst = W2B;           off = i - M4; }
  else if (i < 3 * M4)      { src = x;  dst = XB;            off = i - 2 * M4; }
  else if (i < 3 * M4 + M1) { src = wq; dst = WQKV;          off = i - 3 * M4; }
  else if (i < 3 * M4 + 2 * M1) { src = wk; dst = WQKV + M1;     off = i - 3 * M4 - M1; }
  else if (i < 3 * M4 + 3 * M1) { src = wv; dst = WQKV + 2 * M1; off = i - 3 * M4 - 2 * M1; }
  else                          { src = wo; dst = WOB;           off = i - 3 * M4 - 3 * M1; }
  fx4 v = *(const fx4*)(src + off);
  bfx4 o;
#pragma unroll
  for (int j = 0; j < 4; ++j) o[j] = (__bf16)v[j];
  *(bfx4*)(dst + off) = o;
}

extern "C" void kernel_launch(void* const* d_in, const int* in_sizes, int n_in,
                              void* d_out, int out_size, void* d_ws, size_t ws_size,
                              hipStream_t stream)
{
  const float* x   = (const float*)d_in[0];
  const int*   mask= (const int*)d_in[1];
  const float* wq  = (const float*)d_in[2];
  const float* bq  = (const float*)d_in[3];
  const float* wk  = (const float*)d_in[4];
  const float* bk  = (const float*)d_in[5];
  const float* wv  = (const float*)d_in[6];
  const float* bv  = (const float*)d_in[7];
  const float* wo  = (const float*)d_in[8];
  const float* bo  = (const float*)d_in[9];
  const float* w1  = (const float*)d_in[10];
  const float* b1  = (const float*)d_in[11];
  const float* w2  = (const float*)d_in[12];
  const float* b2  = (const float*)d_in[13];
  const float* g1  = (const float*)d_in[14];
  const float* be1 = (const float*)d_in[15];
  const float* g2  = (const float*)d_in[16];
  const float* be2 = (const float*)d_in[17];

  float* outx  = (float*)d_out;
  float* attnF = outx + (size_t)Bc * Sc * Dc;

  const size_t MB = 1ull << 20;
  char* ws = (char*)d_ws;
  __bf16* XB   = (__bf16*)(ws + 0  * MB);  // 8 MB
  __bf16* WQKV = (__bf16*)(ws + 8  * MB);  // 6 MB
  __bf16* WOB  = (__bf16*)(ws + 14 * MB);  // 2 MB
  __bf16* W1B  = (__bf16*)(ws + 16 * MB);  // 8 MB
  __bf16* W2B  = (__bf16*)(ws + 24 * MB);  // 8 MB
  __bf16* QB   = (__bf16*)(ws + 32 * MB);  // 8 MB
  __bf16* KB   = (__bf16*)(ws + 40 * MB);  // 8 MB
  __bf16* VT   = (__bf16*)(ws + 48 * MB);  // 8 MB
  __bf16* AO   = (__bf16*)(ws + 56 * MB);  // 8 MB
  __bf16* H1   = (__bf16*)(ws + 32 * MB);  // 32 MB overlays dead QB/KB/VT/AO
  __bf16* YB   = (__bf16*)(ws + 72 * MB);  // 8 MB
  unsigned long long* PK = (unsigned long long*)(ws + 80 * MB); // 1 MB
  float*  PF   = (float*)(ws + 88 * MB);   // 2 x 16 MB split-K partials

  const int MT = Bc * Sc;
  dim3 blk(256);

  prep<<<dim3(49152), blk, 0, stream>>>(w1, w2, x, wq, wk, wv, wo, mask,
                                        W1B, W2B, XB, WQKV, WOB, PK);

  gemm8<M_QKV><<<dim3(3 * Dc / 256, MT / 256), dim3(512), 0, stream>>>(
      XB, WQKV, bq, bk, bv, QB, KB, VT, MT, 3 * Dc, Dc);

  // QBLK=128 8-wave fattn: 512 blocks, 1/CU (98 KB LDS), 8 waves/CU
  fattn<<<dim3(16, 32), dim3(512), 0, stream>>>(QB, KB, VT, PK, attnF, AO);

  // AO-proj: 256x128 8-phase split-K x2
  gemm8_sk<<<dim3(Dc / 128, MT / 256, 2), dim3(512), 0, stream>>>(
      AO, WOB, PF, MT, Dc, Dc, Dc / 2);
  ln_comb<<<dim3(MT), blk, 0, stream>>>(PF, PF + (size_t)MT * Dc, bo, XB,
                                        g1, be1, YB, nullptr);

  gemm8<M_GELU><<<dim3(DFFc / 256, MT / 256), dim3(512), 0, stream>>>(
      YB, W1B, b1, nullptr, nullptr, H1, nullptr, nullptr, MT, DFFc, Dc);

  // FFN2: 256x128 8-phase split-K x2
  gemm8_sk<<<dim3(Dc / 128, MT / 256, 2), dim3(512), 0, stream>>>(
      H1, W2B, PF, MT, Dc, DFFc, DFFc / 2);
  ln_comb<<<dim3(MT), blk, 0, stream>>>(PF, PF + (size_t)MT * Dc, b2, YB,
                                        g2, be2, nullptr, outx);
}

// Round 15
// 389.258 us; speedup vs baseline: 1.0313x; 1.0313x over previous
//
#include <hip/hip_runtime.h>
#include <cmath>

#define Bc 2
#define Sc 2048
#define Dc 1024
#define Hc 16
#define DKc 64
#define DFFc 4096
#define NT (Sc / 128)

typedef __bf16    bfx8 __attribute__((ext_vector_type(8)));
typedef __bf16    bfx4 __attribute__((ext_vector_type(4)));
typedef float     fx4  __attribute__((ext_vector_type(4)));

#define QSC 0.18033688011112042f   // 0.125 * log2(e)

__device__ inline void gload_lds16(const void* g, void* l) {
  __builtin_amdgcn_global_load_lds((const __attribute__((address_space(1))) void*)g,
                                   (__attribute__((address_space(3))) void*)l, 16, 0, 0);
}

enum { M_QKV = 0, M_GELU = 3 };

// st_16x32-style fragment read (1 KB per 16-row x 32-col subtile)
__device__ inline bfx8 rd_frag(const char* matbase, int r, int kk) {
  int inner = (r & 15) * 64 + (kk & 31) * 2;
  int byte = (((r >> 4) * 2 + (kk >> 5)) << 10) + (inner ^ ((r & 8) ? 32 : 0));
  return *(const bfx8*)(matbase + byte);
}

// ---------------- 256x256 8-phase GEMM (T2+T3+T4+T5) ----------------
template<int MODE>
__global__ __launch_bounds__(512, 2)
void gemm8(const __bf16* __restrict__ A, const __bf16* __restrict__ Bw,
           const float* __restrict__ bias, const float* __restrict__ bias2,
           const float* __restrict__ bias3,
           void* __restrict__ outp, void* __restrict__ outp2,
           void* __restrict__ outp3, int M, int N, int K)
{
  __shared__ char lds[131072];
  const int tid = threadIdx.x, wave = tid >> 6, lane = tid & 63;
  const int l16 = lane & 15, l4 = lane >> 4;
  const int wr = wave >> 2, wc = wave & 3;

  const int gx = gridDim.x, nwg = gx * gridDim.y;
  const int bid = blockIdx.y * gx + blockIdx.x;
  const int swz = (bid & 7) * (nwg >> 3) + (bid >> 3);
  const int bm = (swz / gx) * 256, bn = (swz % gx) * 256;

  const int nkt = K >> 6;

  fx4 acc[8][4] = {};

  auto stage_tile = [&](int kt, int buf) {
#pragma unroll
    for (int u = 0; u < 4; ++u) {
      const __bf16* gsrc = (u < 2 ? A + (long)(bm + (u & 1) * 128) * K
                                  : Bw + (long)(bn + (u & 1) * 128) * K) + kt * 64;
      char* dst = lds + (u < 2 ? 0 : 65536) + buf * 32768 + (u & 1) * 16384;
#pragma unroll
      for (int i = 0; i < 2; ++i) {
        int c = i * 512 + tid;
        int sc = c ^ (((c >> 5) & 1) << 1);
        int s = sc >> 6, rin = (sc & 63) >> 2, cch = sc & 3;
        gload_lds16(gsrc + (long)((s >> 1) * 16 + rin) * K + (s & 1) * 32 + cch * 8,
                    dst + c * 16);
      }
    }
  };

  stage_tile(0, 0);
  asm volatile("s_waitcnt vmcnt(0)" ::: "memory");
  __builtin_amdgcn_s_barrier();

  bfx8 af[4][2], bfA[2][2], bfB[2][2];

  for (int kt = 0; kt < nkt; ++kt) {
    const int buf = kt & 1;
    const char* Ab = lds + buf * 32768;
    const char* Bb = lds + 65536 + buf * 32768;

#pragma unroll
    for (int m = 0; m < 4; ++m)
#pragma unroll
      for (int ks = 0; ks < 2; ++ks)
        af[m][ks] = rd_frag(Ab, wr * 128 + m * 16 + l16, ks * 32 + l4 * 8);
#pragma unroll
    for (int n = 0; n < 2; ++n)
#pragma unroll
      for (int ks = 0; ks < 2; ++ks)
        bfA[n][ks] = rd_frag(Bb, wc * 64 + n * 16 + l16, ks * 32 + l4 * 8);
    if (kt + 1 < nkt) stage_tile(kt + 1, buf ^ 1);
    __builtin_amdgcn_s_barrier();
    __builtin_amdgcn_s_setprio(1);
#pragma unroll
    for (int m = 0; m < 4; ++m)
#pragma unroll
      for (int n = 0; n < 2; ++n)
#pragma unroll
        for (int ks = 0; ks < 2; ++ks)
          acc[m][n] = __builtin_amdgcn_mfma_f32_16x16x32_bf16(af[m][ks], bfA[n][ks], acc[m][n], 0, 0, 0);
    __builtin_amdgcn_s_setprio(0);
    __builtin_amdgcn_s_barrier();

#pragma unroll
    for (int n = 0; n < 2; ++n)
#pragma unroll
      for (int ks = 0; ks < 2; ++ks)
        bfB[n][ks] = rd_frag(Bb, wc * 64 + 32 + n * 16 + l16, ks * 32 + l4 * 8);
    __builtin_amdgcn_s_barrier();
    __builtin_amdgcn_s_setprio(1);
#pragma unroll
    for (int m = 0; m < 4; ++m)
#pragma unroll
      for (int n = 0; n < 2; ++n)
#pragma unroll
        for (int ks = 0; ks < 2; ++ks)
          acc[m][2 + n] = __builtin_amdgcn_mfma_f32_16x16x32_bf16(af[m][ks], bfB[n][ks], acc[m][2 + n], 0, 0, 0);
    __builtin_amdgcn_s_setprio(0);
    __builtin_amdgcn_s_barrier();

#pragma unroll
    for (int m = 0; m < 4; ++m)
#pragma unroll
      for (int ks = 0; ks < 2; ++ks)
        af[m][ks] = rd_frag(Ab, wr * 128 + 64 + m * 16 + l16, ks * 32 + l4 * 8);
    __builtin_amdgcn_s_barrier();
    __builtin_amdgcn_s_setprio(1);
#pragma unroll
    for (int m = 0; m < 4; ++m)
#pragma unroll
      for (int n = 0; n < 2; ++n)
#pragma unroll
        for (int ks = 0; ks < 2; ++ks)
          acc[4 + m][n] = __builtin_amdgcn_mfma_f32_16x16x32_bf16(af[m][ks], bfA[n][ks], acc[4 + m][n], 0, 0, 0);
    __builtin_amdgcn_s_setprio(0);
    __builtin_amdgcn_s_barrier();

    __builtin_amdgcn_s_setprio(1);
#pragma unroll
    for (int m = 0; m < 4; ++m)
#pragma unroll
      for (int n = 0; n < 2; ++n)
#pragma unroll
        for (int ks = 0; ks < 2; ++ks)
          acc[4 + m][2 + n] = __builtin_amdgcn_mfma_f32_16x16x32_bf16(af[m][ks], bfB[n][ks], acc[4 + m][2 + n], 0, 0, 0);
    __builtin_amdgcn_s_setprio(0);
    asm volatile("s_waitcnt vmcnt(0)" ::: "memory");
    __builtin_amdgcn_sched_barrier(0);
    __builtin_amdgcn_s_barrier();
  }

#pragma unroll
  for (int m = 0; m < 8; ++m) {
#pragma unroll
    for (int n = 0; n < 4; ++n) {
      const int gr0 = bm + wr * 128 + m * 16 + l4 * 4;
      const int gc  = bn + wc * 64 + n * 16 + l16;
      float bv;
      if constexpr (MODE == M_QKV)
        bv = (gc < 1024) ? bias[gc] : (gc < 2048) ? bias2[gc - 1024] : bias3[gc - 2048];
      else
        bv = bias[gc];
#pragma unroll
      for (int j = 0; j < 4; ++j) {
        const int gr = gr0 + j;
        float v = acc[m][n][j] + bv;
        if constexpr (MODE == M_QKV) {
          int qkv = gc >> 10, col = gc & 1023;
          int b = gr >> 11, s = gr & 2047, h = col >> 6, dk = col & 63;
          if (qkv == 0)   // Q pre-scaled by 0.125*log2(e) so fattn uses exp2
            ((__bf16*)outp)[(((long)(b * Hc + h)) * Sc + s) * DKc + dk] = (__bf16)(v * QSC);
          else if (qkv == 1)
            ((__bf16*)outp2)[(((long)(b * Hc + h)) * Sc + s) * DKc + dk] = (__bf16)v;
          else
            ((__bf16*)outp3)[(((long)(b * Hc + h)) * DKc + dk) * Sc + s] = (__bf16)v;
        } else { // M_GELU
          float t = 0.5f * v * (1.0f + erff(v * 0.70710678118654752f));
          ((__bf16*)outp)[(long)gr * N + gc] = (__bf16)t;
        }
      }
    }
  }
}

// ---- 256x128 8-phase split-K GEMM -> f32 partials (nt store) ----
// 8 waves 2M x 4N, wave tile 128x32. LDS 96 KB: A 2x32K @0, B 2x16K @65536.
__global__ __launch_bounds__(512, 2)
void gemm8_sk(const __bf16* __restrict__ A, const __bf16* __restrict__ Bw,
              float* __restrict__ rawp, int M, int N, int K, int kchunk)
{
  __shared__ char lds[98304];
  const int tid = threadIdx.x, wave = tid >> 6, lane = tid & 63;
  const int l16 = lane & 15, l4 = lane >> 4;
  const int wr = wave >> 2, wc = wave & 3;

  const int gx = gridDim.x, nwg = gx * gridDim.y;   // 2D tile grid (z = split-K)
  const int bid = blockIdx.y * gx + blockIdx.x;
  const int swz = (bid & 7) * (nwg >> 3) + (bid >> 3);
  const int bm = (swz / gx) * 256, bn = (swz % gx) * 128;
  const int kz = blockIdx.z;
  const int kt0 = (kz * kchunk) >> 6;
  const int nkt = kchunk >> 6;

  fx4 acc[8][2] = {};

  auto stage_tile = [&](int kt, int buf) {
#pragma unroll
    for (int u = 0; u < 3; ++u) {
      const __bf16* gsrc = (u < 2 ? A + (long)(bm + u * 128) * K
                                  : Bw + (long)bn * K) + kt * 64;
      char* dst = (u < 2) ? lds + buf * 32768 + u * 16384
                          : lds + 65536 + buf * 16384;
#pragma unroll
      for (int i = 0; i < 2; ++i) {
        int c = i * 512 + tid;
        int sc = c ^ (((c >> 5) & 1) << 1);
        int s = sc >> 6, rin = (sc & 63) >> 2, cch = sc & 3;
        gload_lds16(gsrc + (long)((s >> 1) * 16 + rin) * K + (s & 1) * 32 + cch * 8,
                    dst + c * 16);
      }
    }
  };

  stage_tile(kt0, 0);
  asm volatile("s_waitcnt vmcnt(0)" ::: "memory");
  __builtin_amdgcn_s_barrier();

  bfx8 af[4][2], bfA[2], bfB[2];

  for (int t = 0; t < nkt; ++t) {
    const int buf = t & 1;
    const char* Ab = lds + buf * 32768;
    const char* Bb = lds + 65536 + buf * 16384;

    // phase 1: quadrant (m0-3, n0)
#pragma unroll
    for (int m = 0; m < 4; ++m)
#pragma unroll
      for (int ks = 0; ks < 2; ++ks)
        af[m][ks] = rd_frag(Ab, wr * 128 + m * 16 + l16, ks * 32 + l4 * 8);
#pragma unroll
    for (int ks = 0; ks < 2; ++ks)
      bfA[ks] = rd_frag(Bb, wc * 32 + l16, ks * 32 + l4 * 8);
    if (t + 1 < nkt) stage_tile(kt0 + t + 1, buf ^ 1);
    __builtin_amdgcn_s_barrier();
    __builtin_amdgcn_s_setprio(1);
#pragma unroll
    for (int m = 0; m < 4; ++m)
#pragma unroll
      for (int ks = 0; ks < 2; ++ks)
        acc[m][0] = __builtin_amdgcn_mfma_f32_16x16x32_bf16(af[m][ks], bfA[ks], acc[m][0], 0, 0, 0);
    __builtin_amdgcn_s_setprio(0);
    __builtin_amdgcn_s_barrier();

    // phase 2: quadrant (m0-3, n1)
#pragma unroll
    for (int ks = 0; ks < 2; ++ks)
      bfB[ks] = rd_frag(Bb, wc * 32 + 16 + l16, ks * 32 + l4 * 8);
    __builtin_amdgcn_s_barrier();
    __builtin_amdgcn_s_setprio(1);
#pragma unroll
    for (int m = 0; m < 4; ++m)
#pragma unroll
      for (int ks = 0; ks < 2; ++ks)
        acc[m][1] = __builtin_amdgcn_mfma_f32_16x16x32_bf16(af[m][ks], bfB[ks], acc[m][1], 0, 0, 0);
    __builtin_amdgcn_s_setprio(0);
    __builtin_amdgcn_s_barrier();

    // phase 3: quadrant (m4-7, n0)
#pragma unroll
    for (int m = 0; m < 4; ++m)
#pragma unroll
      for (int ks = 0; ks < 2; ++ks)
        af[m][ks] = rd_frag(Ab, wr * 128 + 64 + m * 16 + l16, ks * 32 + l4 * 8);
    __builtin_amdgcn_s_barrier();
    __builtin_amdgcn_s_setprio(1);
#pragma unroll
    for (int m = 0; m < 4; ++m)
#pragma unroll
      for (int ks = 0; ks < 2; ++ks)
        acc[4 + m][0] = __builtin_amdgcn_mfma_f32_16x16x32_bf16(af[m][ks], bfA[ks], acc[4 + m][0], 0, 0, 0);
    __builtin_amdgcn_s_setprio(0);
    __builtin_amdgcn_s_barrier();

    // phase 4: quadrant (m4-7, n1)
    __builtin_amdgcn_s_setprio(1);
#pragma unroll
    for (int m = 0; m < 4; ++m)
#pragma unroll
      for (int ks = 0; ks < 2; ++ks)
        acc[4 + m][1] = __builtin_amdgcn_mfma_f32_16x16x32_bf16(af[m][ks], bfB[ks], acc[4 + m][1], 0, 0, 0);
    __builtin_amdgcn_s_setprio(0);
    asm volatile("s_waitcnt vmcnt(0)" ::: "memory");
    __builtin_amdgcn_sched_barrier(0);
    __builtin_amdgcn_s_barrier();
  }

#pragma unroll
  for (int m = 0; m < 8; ++m) {
#pragma unroll
    for (int n = 0; n < 2; ++n) {
      const int gr0 = bm + wr * 128 + m * 16 + l4 * 4;
      const int gc  = bn + wc * 32 + n * 16 + l16;
#pragma unroll
      for (int j = 0; j < 4; ++j)
        __builtin_nontemporal_store(acc[m][n][j],
            &rawp[(long)kz * M * N + (long)(gr0 + j) * N + gc]);
    }
  }
}

// -------- fused two-pass flash attention, z-local XCD remap ----------
__global__ __launch_bounds__(256)
void fattn(const __bf16* __restrict__ Qg, const __bf16* __restrict__ Kg,
           const __bf16* __restrict__ Vg, const unsigned long long* __restrict__ pk,
           float* __restrict__ wout, __bf16* __restrict__ aout)
{
  const int bid = blockIdx.y * 32 + blockIdx.x;
  const int c = bid & 7, idx = bid >> 3;
  const int z = c + 8 * (idx >> 5);        // 4 z's per XCD: K+V = 4 MB = L2
  const int qb = (idx & 31) * 64;
  const int bz = z >> 4, h = z & 15;
  const int tid = threadIdx.x, w = tid >> 6, lane = tid & 63;
  const int l16 = lane & 15, l4 = lane >> 4;

  __shared__ alignas(16) __bf16 Qs[64 * 64];
  __shared__ alignas(16) __bf16 Ks[2][128 * 64];
  __shared__ alignas(16) __bf16 Vs[64 * 128];
  __shared__ alignas(16) __bf16 Ps[64 * 136];

  const __bf16* Qz = Qg + ((long)z * Sc + qb) * DKc;
  const __bf16* Kz = Kg + (long)z * Sc * DKc;
  const __bf16* Vz = Vg + (long)z * DKc * Sc;

  auto stageK = [&](int kt, int buf) {
#pragma unroll
    for (int i = 0; i < 4; ++i) {
      int ch = (w * 4 + i) * 64 + lane;
      int row = ch >> 3, c16 = ch & 7;
      gload_lds16(Kz + (long)(kt * 128 + row) * DKc + ((c16 ^ (row & 7)) * 8),
                  (char*)Ks[buf] + ch * 16);
    }
  };
  auto stageV = [&](int kt) {
#pragma unroll
    for (int i = 0; i < 4; ++i) {
      int ch = (w * 4 + i) * 64 + lane;
      int row = ch >> 4, c16 = ch & 15;
      gload_lds16(Vz + (long)row * Sc + kt * 128 + ((c16 ^ (row & 7)) * 8),
                  (char*)Vs + ch * 16);
    }
  };

#pragma unroll
  for (int i = 0; i < 2; ++i) {
    int ch = (w * 2 + i) * 64 + lane;
    int row = ch >> 3, c16 = ch & 7;
    gload_lds16(Qz + (long)row * DKc + ((c16 ^ (row & 7)) * 8), (char*)Qs + ch * 16);
  }
  stageK(0, 0);
  __syncthreads();

  const int qr = w * 16 + l16;
  bfx8 aq[2];
#pragma unroll
  for (int ks = 0; ks < 2; ++ks) {
    int c16 = ks * 4 + l4;
    aq[ks] = *(const bfx8*)((const char*)Qs + qr * 128 + ((c16 ^ (qr & 7)) * 16));
  }

  const long pkbase = ((long)bz * Sc + qb + w * 16 + l4 * 4) * 32;

  float l[4] = {0.f, 0.f, 0.f, 0.f};

  // ---------------- pass A: row denominators (m = 0 proxy) ----------------
  for (int kt = 0; kt < NT; ++kt) {
    const int cur = kt & 1;
    stageK(kt + 1 < NT ? kt + 1 : 0, cur ^ 1);
    fx4 acc[8];
    __builtin_amdgcn_s_setprio(1);
#pragma unroll
    for (int n = 0; n < 8; ++n) {
      int kr = n * 16 + l16;
      fx4 a = {};
#pragma unroll
      for (int ks = 0; ks < 2; ++ks) {
        int c16 = ks * 4 + l4;
        bfx8 bk = *(const bfx8*)((const char*)Ks[cur] + kr * 128 + ((c16 ^ (kr & 7)) * 16));
        a = __builtin_amdgcn_mfma_f32_16x16x32_bf16(aq[ks], bk, a, 0, 0, 0);
      }
      acc[n] = a;
    }
    __builtin_amdgcn_s_setprio(0);
#pragma unroll
    for (int j = 0; j < 4; ++j) {
      unsigned long long m0 = pk[pkbase + j * 32 + kt * 2];
      unsigned long long m1 = pk[pkbase + j * 32 + kt * 2 + 1];
      float ps = 0.f;
#pragma unroll
      for (int n = 0; n < 8; ++n) {
        unsigned long long mw = (n < 4) ? m0 : m1;
        int bit = (n & 3) * 16 + l16;
        float e = exp2f(acc[n][j]);      // Q pre-scaled by 0.125*log2e
        ps += ((mw >> bit) & 1) ? e : 0.f;
      }
      l[j] += ps;
    }
    __syncthreads();
  }

  float invl[4];
#pragma unroll
  for (int j = 0; j < 4; ++j) {
    float s = l[j];
#pragma unroll
    for (int o = 1; o < 16; o <<= 1) s += __shfl_xor(s, o, 64);
    invl[j] = 1.0f / s;
  }

  fx4 O[4] = {};

  // ------------- pass B: weights (nt store) + PV -------------
  for (int kt = 0; kt < NT; ++kt) {
    const int cur = kt & 1;
    stageV(kt);
    fx4 acc[8];
    __builtin_amdgcn_s_setprio(1);
#pragma unroll
    for (int n = 0; n < 8; ++n) {
      int kr = n * 16 + l16;
      fx4 a = {};
#pragma unroll
      for (int ks = 0; ks < 2; ++ks) {
        int c16 = ks * 4 + l4;
        bfx8 bk = *(const bfx8*)((const char*)Ks[cur] + kr * 128 + ((c16 ^ (kr & 7)) * 16));
        a = __builtin_amdgcn_mfma_f32_16x16x32_bf16(aq[ks], bk, a, 0, 0, 0);
      }
      acc[n] = a;
    }
    __builtin_amdgcn_s_setprio(0);
#pragma unroll
    for (int j = 0; j < 4; ++j) {
      unsigned long long m0 = pk[pkbase + j * 32 + kt * 2];
      unsigned long long m1 = pk[pkbase + j * 32 + kt * 2 + 1];
      __bf16* prow = Ps + (w * 16 + l4 * 4 + j) * 136;
#pragma unroll
      for (int n = 0; n < 8; ++n) {
        unsigned long long mw = (n < 4) ? m0 : m1;
        int bit = (n & 3) * 16 + l16;
        float wv = ((mw >> bit) & 1) ? exp2f(acc[n][j]) * invl[j] : 0.f;
        prow[n * 16 + l16] = (__bf16)wv;
      }
    }
    __syncthreads();
    if (kt + 1 < NT) stageK(kt + 1, cur ^ 1);
    // nontemporal weight store: never re-read -> don't evict K/V from L2
    float* wbase = wout + ((long)z * Sc + qb) * Sc + kt * 128;
#pragma unroll
    for (int it = 0; it < 8; ++it) {
      int idx2 = it * 256 + tid;
      int row = idx2 >> 5, cc = idx2 & 31;
      bfx4 p4 = *(const bfx4*)(Ps + row * 136 + cc * 4);
      fx4 o;
      o[0] = (float)p4[0]; o[1] = (float)p4[1]; o[2] = (float)p4[2]; o[3] = (float)p4[3];
      __builtin_nontemporal_store(o, (fx4*)(wbase + (long)row * Sc + cc * 4));
    }
    __builtin_amdgcn_s_setprio(1);
#pragma unroll
    for (int ks2 = 0; ks2 < 4; ++ks2) {
      bfx8 pa = *(const bfx8*)(Ps + qr * 136 + ks2 * 32 + l4 * 8);
#pragma unroll
      for (int n = 0; n < 4; ++n) {
        int vr = n * 16 + l16;
        int c16 = ks2 * 4 + l4;
        bfx8 bv = *(const bfx8*)((const char*)Vs + vr * 256 + ((c16 ^ (vr & 7)) * 16));
        O[n] = __builtin_amdgcn_mfma_f32_16x16x32_bf16(pa, bv, O[n], 0, 0, 0);
      }
    }
    __builtin_amdgcn_s_setprio(0);
    __syncthreads();
  }

#pragma unroll
  for (int n = 0; n < 4; ++n) {
#pragma unroll
    for (int j = 0; j < 4; ++j) {
      int qg = qb + w * 16 + l4 * 4 + j;
      aout[((long)bz * Sc + qg) * Dc + h * DKc + n * 16 + l16] = (__bf16)O[n][j];
    }
  }
}

__device__ inline float waveSum(float v) {
#pragma unroll
  for (int o = 32; o > 0; o >>= 1) v += __shfl_xor(v, o, 64);
  return v;
}

// LayerNorm combining split-K partials + bias + bf16 residual
__global__ __launch_bounds__(256)
void ln_comb(const float* __restrict__ p0, const float* __restrict__ p1,
             const float* __restrict__ bias, const __bf16* __restrict__ resid,
             const float* __restrict__ g, const float* __restrict__ be,
             __bf16* __restrict__ ob, float* __restrict__ of)
{
  const long row = blockIdx.x;
  const int tid = threadIdx.x, wave = tid >> 6, lane = tid & 63;
  fx4 a = *(const fx4*)(p0 + row * Dc + tid * 4);
  fx4 b = *(const fx4*)(p1 + row * Dc + tid * 4);
  fx4 bi = *(const fx4*)(bias + tid * 4);
  bfx4 r4 = *(const bfx4*)(resid + row * Dc + tid * 4);
  const float v0 = a[0] + b[0] + bi[0] + (float)r4[0];
  const float v1 = a[1] + b[1] + bi[1] + (float)r4[1];
  const float v2 = a[2] + b[2] + bi[2] + (float)r4[2];
  const float v3 = a[3] + b[3] + bi[3] + (float)r4[3];
  float s = v0 + v1 + v2 + v3;
  s = waveSum(s);
  __shared__ float sm[4];
  if (lane == 0) sm[wave] = s;
  __syncthreads();
  const float mean = (sm[0] + sm[1] + sm[2] + sm[3]) * (1.0f / Dc);
  const float d0 = v0 - mean, d1 = v1 - mean, d2 = v2 - mean, d3 = v3 - mean;
  float q = d0 * d0 + d1 * d1 + d2 * d2 + d3 * d3;
  q = waveSum(q);
  __syncthreads();
  if (lane == 0) sm[wave] = q;
  __syncthreads();
  const float var = (sm[0] + sm[1] + sm[2] + sm[3]) * (1.0f / (Dc - 1));
  const float inv = 1.0f / (sqrtf(var) + 1e-6f);
  const float r0 = g[tid * 4 + 0] * d0 * inv + be[tid * 4 + 0];
  const float r1 = g[tid * 4 + 1] * d1 * inv + be[tid * 4 + 1];
  const float r2 = g[tid * 4 + 2] * d2 * inv + be[tid * 4 + 2];
  const float r3 = g[tid * 4 + 3] * d3 * inv + be[tid * 4 + 3];
  if (ob) {
    bfx4 o; o[0] = (__bf16)r0; o[1] = (__bf16)r1; o[2] = (__bf16)r2; o[3] = (__bf16)r3;
    *(bfx4*)(ob + row * Dc + tid * 4) = o;
  }
  if (of) {
    fx4 o; o[0] = r0; o[1] = r1; o[2] = r2; o[3] = r3;
    *(fx4*)(of + row * Dc + tid * 4) = o;
  }
}

// casts (blocks 0..16383) + mask bit-pack (blocks 16384..49151)
__global__ __launch_bounds__(256)
void prep(const float* __restrict__ w1, const float* __restrict__ w2,
          const float* __restrict__ x,  const float* __restrict__ wq,
          const float* __restrict__ wk, const float* __restrict__ wv,
          const float* __restrict__ wo, const int* __restrict__ mask,
          __bf16* __restrict__ W1B, __bf16* __restrict__ W2B,
          __bf16* __restrict__ XB,  __bf16* __restrict__ WQKV,
          __bf16* __restrict__ WOB, unsigned long long* __restrict__ pkk)
{
  const int bidx = blockIdx.x;
  if (bidx >= 16384) {
    long wid = (long)(bidx - 16384) * 4 + (threadIdx.x >> 6);
    int lane = threadIdx.x & 63;
    int v = mask[wid * 64 + lane];
    unsigned long long b = __ballot(v != 0);
    if (lane == 0) pkk[wid] = b;
    return;
  }
  const long M4 = 4ll * 1024 * 1024, M1 = 1024 * 1024;
  long i = ((long)bidx * 256 + threadIdx.x) * 4;
  const float* src; __bf16* dst; long off;
  if      (i < M4)          { src = w1; dst = W1B;           off = i; }
  else if (i < 2 * M4)      { src = w2; dst = W2B;           off = i - M4; }
  else if (i < 3 * M4)      { src = x;  dst = XB;            off = i - 2 * M4; }
  else if (i < 3 * M4 + M1) { src = wq; dst = WQKV;          off = i - 3 * M4; }
  else if (i < 3 * M4 + 2 * M1) { src = wk; dst = WQKV + M1;     off = i - 3 * M4 - M1; }
  else if (i < 3 * M4 + 3 * M1) { src = wv; dst = WQKV + 2 * M1; off = i - 3 * M4 - 2 * M1; }
  else                          { src = wo; dst = WOB;           off = i - 3 * M4 - 3 * M1; }
  fx4 v = *(const fx4*)(src + off);
  bfx4 o;
#pragma unroll
  for (int j = 0; j < 4; ++j) o[j] = (__bf16)v[j];
  *(bfx4*)(dst + off) = o;
}

extern "C" void kernel_launch(void* const* d_in, const int* in_sizes, int n_in,
                              void* d_out, int out_size, void* d_ws, size_t ws_size,
                              hipStream_t stream)
{
  const float* x   = (const float*)d_in[0];
  const int*   mask= (const int*)d_in[1];
  const float* wq  = (const float*)d_in[2];
  const float* bq  = (const float*)d_in[3];
  const float* wk  = (const float*)d_in[4];
  const float* bk  = (const float*)d_in[5];
  const float* wv  = (const float*)d_in[6];
  const float* bv  = (const float*)d_in[7];
  const float* wo  = (const float*)d_in[8];
  const float* bo  = (const float*)d_in[9];
  const float* w1  = (const float*)d_in[10];
  const float* b1  = (const float*)d_in[11];
  const float* w2  = (const float*)d_in[12];
  const float* b2  = (const float*)d_in[13];
  const float* g1  = (const float*)d_in[14];
  const float* be1 = (const float*)d_in[15];
  const float* g2  = (const float*)d_in[16];
  const float* be2 = (const float*)d_in[17];

  float* outx  = (float*)d_out;
  float* attnF = outx + (size_t)Bc * Sc * Dc;

  const size_t MB = 1ull << 20;
  char* ws = (char*)d_ws;
  __bf16* XB   = (__bf16*)(ws + 0  * MB);  // 8 MB
  __bf16* WQKV = (__bf16*)(ws + 8  * MB);  // 6 MB
  __bf16* WOB  = (__bf16*)(ws + 14 * MB);  // 2 MB
  __bf16* W1B  = (__bf16*)(ws + 16 * MB);  // 8 MB
  __bf16* W2B  = (__bf16*)(ws + 24 * MB);  // 8 MB
  __bf16* QB   = (__bf16*)(ws + 32 * MB);  // 8 MB
  __bf16* KB   = (__bf16*)(ws + 40 * MB);  // 8 MB
  __bf16* VT   = (__bf16*)(ws + 48 * MB);  // 8 MB
  __bf16* AO   = (__bf16*)(ws + 56 * MB);  // 8 MB
  __bf16* H1   = (__bf16*)(ws + 32 * MB);  // 32 MB overlays dead QB/KB/VT/AO
  __bf16* YB   = (__bf16*)(ws + 72 * MB);  // 8 MB
  unsigned long long* PK = (unsigned long long*)(ws + 80 * MB); // 1 MB
  float*  PF   = (float*)(ws + 88 * MB);   // 2 x 16 MB split-K partials

  const int MT = Bc * Sc;
  dim3 blk(256);

  prep<<<dim3(49152), blk, 0, stream>>>(w1, w2, x, wq, wk, wv, wo, mask,
                                        W1B, W2B, XB, WQKV, WOB, PK);

  gemm8<M_QKV><<<dim3(3 * Dc / 256, MT / 256), dim3(512), 0, stream>>>(
      XB, WQKV, bq, bk, bv, QB, KB, VT, MT, 3 * Dc, Dc);

  fattn<<<dim3(32, 32), blk, 0, stream>>>(QB, KB, VT, PK, attnF, AO);

  // AO-proj: 256x128 8-phase split-K x2 (grid 8x16x2 = 256 blocks, 1/CU)
  gemm8_sk<<<dim3(Dc / 128, MT / 256, 2), dim3(512), 0, stream>>>(
      AO, WOB, PF, MT, Dc, Dc, Dc / 2);
  ln_comb<<<dim3(MT), blk, 0, stream>>>(PF, PF + (size_t)MT * Dc, bo, XB,
                                        g1, be1, YB, nullptr);

  gemm8<M_GELU><<<dim3(DFFc / 256, MT / 256), dim3(512), 0, stream>>>(
      YB, W1B, b1, nullptr, nullptr, H1, nullptr, nullptr, MT, DFFc, Dc);

  // FFN2: 256x128 8-phase split-K x2 (grid 8x16x2 = 256 blocks, 1/CU)
  gemm8_sk<<<dim3(Dc / 128, MT / 256, 2), dim3(512), 0, stream>>>(
      H1, W2B, PF, MT, Dc, DFFc, DFFc / 2);
  ln_comb<<<dim3(MT), blk, 0, stream>>>(PF, PF + (size_t)MT * Dc, b2, YB,
                                        g2, be2, nullptr, outx);
}